// Round 2
// baseline (519.519 us; speedup 1.0000x reference)
//
#include <hip/hip_runtime.h>
#include <hip/hip_bf16.h>
#include <stdint.h>

// ---------------------------------------------------------------------------
// AstrocyteMemoryModule r2: XCD-swizzled big GEMM + transposed vh epilogue +
// LDS-free direct-fragment thin GEMMs for the whole tail.
// ---------------------------------------------------------------------------

typedef __bf16 bf16;
typedef __bf16 bf16x4 __attribute__((ext_vector_type(4)));
typedef __bf16 bf16x8 __attribute__((ext_vector_type(8)));
typedef float f32x4 __attribute__((ext_vector_type(4)));

#define D_ 1024
#define M_ 8192
#define B_ 64
#define H_ 16

static __device__ __forceinline__ void gload16(const void* g, void* l) {
  __builtin_amdgcn_global_load_lds(
      (const __attribute__((address_space(1))) void*)g,
      (__attribute__((address_space(3))) void*)l, 16, 0, 0);
}

// ------------------------------- converts ----------------------------------
// flat-indexed fp32->bf16 convert; section boundaries are all block-aligned.
struct CvtD { const float* src; bf16* dst; int end; int shift; int stride; };
struct CvtA { CvtD d[10]; };

__global__ __launch_bounds__(256) void cvt_flat(CvtA a) {
  int g = blockIdx.x * 256 + threadIdx.x;  // global float4-chunk id
  CvtD dd = a.d[9];
  int begin = a.d[8].end;
#pragma unroll
  for (int t = 8; t >= 0; t--)
    if (g < a.d[t].end) { dd = a.d[t]; begin = t ? a.d[t - 1].end : 0; }
  int i = (g - begin) * 4;
  float4 v = *(const float4*)(dd.src + i);
  int r = i >> dd.shift;
  int c = i - (r << dd.shift);
  bf16x4 o = { (bf16)v.x, (bf16)v.y, (bf16)v.z, (bf16)v.w };
  *(bf16x4*)(dd.dst + (int64_t)r * dd.stride + c) = o;
}

// transpose+convert Wq,Wk,Wv (fp32 DxD -> bf16 transposed), z picks tensor
__global__ __launch_bounds__(256) void transpose_cvt3(
    const float* __restrict__ s0, const float* __restrict__ s1,
    const float* __restrict__ s2, bf16* __restrict__ dst) {
  const float* src = blockIdx.z == 0 ? s0 : blockIdx.z == 1 ? s1 : s2;
  bf16* out = dst + (int64_t)blockIdx.z * D_ * D_;
  __shared__ bf16 tile[32][33];
  int tx = threadIdx.x & 31, ty = threadIdx.x >> 5;
  int r0 = blockIdx.y * 32, c0 = blockIdx.x * 32;
#pragma unroll
  for (int i = 0; i < 32; i += 8)
    tile[ty + i][tx] = (bf16)src[(int64_t)(r0 + ty + i) * D_ + c0 + tx];
  __syncthreads();
#pragma unroll
  for (int i = 0; i < 32; i += 8)
    out[(int64_t)(c0 + ty + i) * D_ + r0 + tx] = tile[tx][ty + i];
}

// bc[z*D+n] = sum_l inproj[z*D+n][l]*b_z[l] + inproj_b[z*D+n]
__global__ __launch_bounds__(256) void bias_combine(
    const float* __restrict__ inw, const float* __restrict__ inb,
    const float* __restrict__ bq, const float* __restrict__ bk,
    const float* __restrict__ bv, float* __restrict__ bc) {
  int z = blockIdx.y, n = blockIdx.x;
  const float* Wi = inw + ((int64_t)z * D_ + n) * D_;
  const float* b = z == 0 ? bq : z == 1 ? bk : bv;
  float acc = 0.f;
  for (int l = threadIdx.x; l < D_; l += 256) acc += Wi[l] * b[l];
#pragma unroll
  for (int m = 32; m; m >>= 1) acc += __shfl_xor(acc, m, 64);
  __shared__ float red[4];
  if ((threadIdx.x & 63) == 0) red[threadIdx.x >> 6] = acc;
  __syncthreads();
  if (threadIdx.x == 0)
    bc[z * D_ + n] = red[0] + red[1] + red[2] + red[3] + inb[z * D_ + n];
}

// ------------------------- big GEMM: C = A @ B^T ---------------------------
// 128x128 tile, BK=32, 4 waves. MODE 0: plain 3D grid, row-major C.
// MODE 1: flat grid 1024 with XCD swizzle (XCD owns an M-band, N fastest);
//         z==0 -> row-major C (kh), z==1 -> transposed Ct[n][m] (vhT).
template <int MODE>
__global__ __launch_bounds__(256) void gemm_big(
    const bf16* __restrict__ A, int lda, int64_t sA,
    const bf16* __restrict__ Bm, int ldb, int64_t sB,
    bf16* __restrict__ C, int ldc, int64_t sC, bf16* __restrict__ Ct,
    const float* __restrict__ bias, int64_t sbias, int K) {
  int m0, n0, z;
  if (MODE == 0) {
    z = blockIdx.z; m0 = blockIdx.y * 128; n0 = blockIdx.x * 128;
  } else {
    int lin = blockIdx.x, xcd = lin & 7, slot = lin >> 3;
    z = slot >> 6;                       // 0..1
    int r = slot & 63;
    m0 = (xcd * 8 + (r >> 3)) * 128;     // XCD owns M-band; A-tile reused 8x
    n0 = (r & 7) * 128;                  // N fastest within the band
  }
  A += (int64_t)z * sA; Bm += (int64_t)z * sB;
  if (bias) bias += (int64_t)z * sbias;
  __shared__ alignas(16) bf16 As[128 * 32];
  __shared__ alignas(16) bf16 Bs[128 * 32];
  const int tid = threadIdx.x, lane = tid & 63, w = tid >> 6;
  const int wm = (w & 1) * 64, wn = (w >> 1) * 64;
  f32x4 acc[4][4] = {};

  int c0 = w * 64 + lane, c1 = (4 + w) * 64 + lane;
  int ra0 = c0 >> 2, qa0 = (c0 & 3) ^ ((ra0 >> 1) & 3);
  int ra1 = c1 >> 2, qa1 = (c1 & 3) ^ ((ra1 >> 1) & 3);
  const bf16* gA0 = A + (int64_t)(m0 + ra0) * lda + qa0 * 8;
  const bf16* gA1 = A + (int64_t)(m0 + ra1) * lda + qa1 * 8;
  const bf16* gB0 = Bm + (int64_t)(n0 + ra0) * ldb + qa0 * 8;
  const bf16* gB1 = Bm + (int64_t)(n0 + ra1) * ldb + qa1 * 8;
  bf16* lA0 = As + w * 512;
  bf16* lA1 = As + (4 + w) * 512;
  bf16* lB0 = Bs + w * 512;
  bf16* lB1 = Bs + (4 + w) * 512;

  const int rl = lane & 15, qq = lane >> 4;
  for (int k0 = 0; k0 < K; k0 += 32) {
    __syncthreads();
    gload16(gA0 + k0, lA0);
    gload16(gA1 + k0, lA1);
    gload16(gB0 + k0, lB0);
    gload16(gB1 + k0, lB1);
    __syncthreads();
    bf16x8 af[4], bv[4];
#pragma unroll
    for (int i = 0; i < 4; i++) {
      int r = wm + i * 16 + rl;
      af[i] = *(const bf16x8*)(As + r * 32 + (qq ^ ((r >> 1) & 3)) * 8);
    }
#pragma unroll
    for (int j = 0; j < 4; j++) {
      int r = wn + j * 16 + rl;
      bv[j] = *(const bf16x8*)(Bs + r * 32 + (qq ^ ((r >> 1) & 3)) * 8);
    }
#pragma unroll
    for (int i = 0; i < 4; i++)
#pragma unroll
      for (int j = 0; j < 4; j++)
        acc[i][j] = __builtin_amdgcn_mfma_f32_16x16x32_bf16(af[i], bv[j],
                                                            acc[i][j], 0, 0, 0);
  }
  if (MODE == 1 && z == 1) {
    // vhT[n][m]: per (i,j) the 4 acc values are consecutive m -> bf16x4 store
#pragma unroll
    for (int j = 0; j < 4; j++) {
      int gn = n0 + wn + j * 16 + rl;
      float bb = bias ? bias[gn] : 0.0f;
#pragma unroll
      for (int i = 0; i < 4; i++) {
        int gm0 = m0 + wm + i * 16 + qq * 4;
        f32x4 a = acc[i][j];
        bf16x4 o = { (bf16)(a[0] + bb), (bf16)(a[1] + bb),
                     (bf16)(a[2] + bb), (bf16)(a[3] + bb) };
        *(bf16x4*)(Ct + (int64_t)gn * M_ + gm0) = o;
      }
    }
  } else {
    C += (int64_t)z * sC;
#pragma unroll
    for (int j = 0; j < 4; j++) {
      int gn = n0 + wn + j * 16 + rl;
      float bb = bias ? bias[gn] : 0.0f;
#pragma unroll
      for (int i = 0; i < 4; i++) {
        int gm0 = m0 + wm + i * 16 + qq * 4;
#pragma unroll
        for (int r = 0; r < 4; r++)
          C[(int64_t)(gm0 + r) * ldc + gn] = (bf16)(acc[i][j][r] + bb);
      }
    }
  }
}

// ---------------- thin GEMM (M=64), no LDS, direct frags -------------------
// A-frag A[m=lane&15][k=quad*8+j] and B-frag B[n=lane&15][k=quad*8+j] are
// single 16B global loads (K-contiguous operands). 4 waves cover 64 rows.
// EPI: 0=none, 1=relu, 2=sigmoid(val)*aux.
template <int UNROLL, int EPI, typename OutT>
__global__ __launch_bounds__(256) void gemm_thin(
    const bf16* __restrict__ A, int lda, int64_t sA,
    const bf16* __restrict__ Bm, int ldb, int64_t sB,
    OutT* __restrict__ C, int ldc, int64_t sC, int64_t sCk,
    const float* __restrict__ bias, float scale,
    const bf16* __restrict__ aux, int ldaux, int klen) {
  const int z = blockIdx.z, kblk = blockIdx.y;
  A += (int64_t)z * sA + (int64_t)kblk * klen;
  Bm += (int64_t)z * sB + (int64_t)kblk * klen;
  C += (int64_t)z * sC + (int64_t)kblk * sCk;
  const int n0 = blockIdx.x * 64;
  const int tid = threadIdx.x, lane = tid & 63, w = tid >> 6;
  const int rl = lane & 15, qq = lane >> 4;
  const bf16* pa = A + (int64_t)(w * 16 + rl) * lda + qq * 8;
  const bf16* pb0 = Bm + (int64_t)(n0 + rl) * ldb + qq * 8;
  const bf16* pb1 = pb0 + (int64_t)16 * ldb;
  const bf16* pb2 = pb0 + (int64_t)32 * ldb;
  const bf16* pb3 = pb0 + (int64_t)48 * ldb;
  f32x4 acc[4] = {};
  for (int k0 = 0; k0 < klen; k0 += 32 * UNROLL) {
    bf16x8 av[UNROLL], bv[UNROLL][4];
#pragma unroll
    for (int u = 0; u < UNROLL; u++) {
      int k = k0 + u * 32;
      av[u] = *(const bf16x8*)(pa + k);
      bv[u][0] = *(const bf16x8*)(pb0 + k);
      bv[u][1] = *(const bf16x8*)(pb1 + k);
      bv[u][2] = *(const bf16x8*)(pb2 + k);
      bv[u][3] = *(const bf16x8*)(pb3 + k);
    }
#pragma unroll
    for (int u = 0; u < UNROLL; u++)
#pragma unroll
      for (int j = 0; j < 4; j++)
        acc[j] = __builtin_amdgcn_mfma_f32_16x16x32_bf16(av[u], bv[u][j],
                                                         acc[j], 0, 0, 0);
  }
#pragma unroll
  for (int j = 0; j < 4; j++) {
    int gn = n0 + j * 16 + rl;
    float bb = bias ? bias[gn] : 0.0f;
#pragma unroll
    for (int r = 0; r < 4; r++) {
      int gm = w * 16 + qq * 4 + r;
      float val = (acc[j][r] + bb) * scale;
      if constexpr (EPI == 1) val = fmaxf(val, 0.0f);
      if constexpr (EPI == 2) {
        float g = 1.0f / (1.0f + __expf(-val));
        val = g * (float)aux[(int64_t)gm * ldaux + gn];
      }
      C[(int64_t)gm * ldc + gn] = (OutT)val;
    }
  }
}

// ------------------------------- softmax -----------------------------------
__global__ __launch_bounds__(256) void softmax_kernel(
    const float* __restrict__ scores, bf16* __restrict__ attn) {
  int row = blockIdx.x;
  const float4* s = (const float4*)(scores + (int64_t)row * M_);
  bf16* a = attn + (int64_t)row * M_;
  int t = threadIdx.x;
  float4 v[8];
  float mx = -3.4e38f;
#pragma unroll
  for (int j = 0; j < 8; j++) {
    v[j] = s[j * 256 + t];
    mx = fmaxf(mx, fmaxf(fmaxf(v[j].x, v[j].y), fmaxf(v[j].z, v[j].w)));
  }
#pragma unroll
  for (int m = 32; m; m >>= 1) mx = fmaxf(mx, __shfl_xor(mx, m, 64));
  __shared__ float red[4];
  if ((t & 63) == 0) red[t >> 6] = mx;
  __syncthreads();
  mx = fmaxf(fmaxf(red[0], red[1]), fmaxf(red[2], red[3]));
  float sum = 0.f;
#pragma unroll
  for (int j = 0; j < 8; j++) {
    v[j].x = __expf(v[j].x - mx); v[j].y = __expf(v[j].y - mx);
    v[j].z = __expf(v[j].z - mx); v[j].w = __expf(v[j].w - mx);
    sum += v[j].x + v[j].y + v[j].z + v[j].w;
  }
#pragma unroll
  for (int m = 32; m; m >>= 1) sum += __shfl_xor(sum, m, 64);
  __syncthreads();
  if ((t & 63) == 0) red[t >> 6] = sum;
  __syncthreads();
  sum = red[0] + red[1] + red[2] + red[3];
  float rinv = 1.0f / sum;
#pragma unroll
  for (int j = 0; j < 8; j++) {
    bf16x4 o = { (bf16)(v[j].x * rinv), (bf16)(v[j].y * rinv),
                 (bf16)(v[j].z * rinv), (bf16)(v[j].w * rinv) };
    *(bf16x4*)(a + (int64_t)(j * 256 + t) * 4) = o;
  }
}

// sum split-K ctx partials: part[h][ks][b][d] -> ctx[b][h*64+d]
__global__ __launch_bounds__(256) void ctx_reduce(const float* __restrict__ part,
                                                  bf16* __restrict__ ctx) {
  int t = blockIdx.x * 256 + threadIdx.x;
  int h = t >> 12, b = (t >> 6) & 63, d = t & 63;
  float s = 0.f;
#pragma unroll
  for (int ks = 0; ks < 8; ks++)
    s += part[((int64_t)(h * 8 + ks) * 64 + b) * 64 + d];
  ctx[(int64_t)b * D_ + h * 64 + d] = (bf16)s;
}

// ------------------------------- launch ------------------------------------
extern "C" void kernel_launch(void* const* d_in, const int* in_sizes, int n_in,
                              void* d_out, int out_size, void* d_ws,
                              size_t ws_size, hipStream_t stream) {
  (void)in_sizes; (void)n_in; (void)out_size;
  const float* x    = (const float*)d_in[0];
  const float* mk   = (const float*)d_in[1];
  const float* mv   = (const float*)d_in[2];
  const float* Wq   = (const float*)d_in[3];
  const float* bq   = (const float*)d_in[4];
  const float* Wk   = (const float*)d_in[5];
  const float* bk   = (const float*)d_in[6];
  const float* Wv   = (const float*)d_in[7];
  const float* bv   = (const float*)d_in[8];
  const float* inw  = (const float*)d_in[9];
  const float* inb  = (const float*)d_in[10];
  const float* outw = (const float*)d_in[11];
  const float* outb = (const float*)d_in[12];
  const float* gW1  = (const float*)d_in[13];
  const float* gb1  = (const float*)d_in[14];
  const float* gW2  = (const float*)d_in[15];
  const float* gb2  = (const float*)d_in[16];
  const float* iW1  = (const float*)d_in[17];
  const float* ib1  = (const float*)d_in[18];
  const float* iW2  = (const float*)d_in[19];
  const float* ib2  = (const float*)d_in[20];

  char* ws = (char*)d_ws;
  size_t off = 0;
  auto alloc = [&](size_t bytes) {
    char* p = ws + off;
    off += (bytes + 255) & ~(size_t)255;
    return p;
  };
  bf16* mkmv  = (bf16*)alloc((size_t)2 * M_ * D_ * 2);  // later aliased: scores
  bf16* inpj  = (bf16*)alloc((size_t)3 * D_ * D_ * 2);
  bf16* WT    = (bf16*)alloc((size_t)3 * D_ * D_ * 2);
  bf16* Wc    = (bf16*)alloc((size_t)3 * D_ * D_ * 2);
  float* bc   = (float*)alloc(3 * D_ * 4);
  bf16* xms   = (bf16*)alloc((size_t)B_ * 2 * D_ * 2);
  bf16* xgm   = (bf16*)alloc((size_t)B_ * 2 * D_ * 2);
  bf16* qh    = (bf16*)alloc((size_t)B_ * D_ * 2);
  bf16* khvh  = (bf16*)alloc((size_t)2 * M_ * D_ * 2);  // only kh region used
  bf16* vhT   = (bf16*)alloc((size_t)M_ * D_ * 2);
  bf16* attn  = (bf16*)alloc((size_t)H_ * B_ * M_ * 2);
  float* part = (float*)alloc((size_t)16 * 8 * 64 * 64 * 4);
  bf16* ctx   = (bf16*)alloc((size_t)B_ * D_ * 2);
  bf16* g1    = (bf16*)alloc((size_t)B_ * D_ * 2);
  bf16* h1    = (bf16*)alloc((size_t)B_ * 2 * D_ * 2);
  bf16* gW1b  = (bf16*)alloc((size_t)D_ * 2 * D_ * 2);
  bf16* gW2b  = (bf16*)alloc((size_t)D_ * D_ * 2);
  bf16* iW1b  = (bf16*)alloc((size_t)2 * D_ * 2 * D_ * 2);
  bf16* iW2b  = (bf16*)alloc((size_t)D_ * 2 * D_ * 2);
  bf16* outwb = (bf16*)alloc((size_t)D_ * D_ * 2);
  float* scores = (float*)mkmv;  // alias: mk/mv bf16 dead after kh/vh GEMM
  if (ws_size < off) return;

  // 1) fp32 -> bf16 converts, exact flat grid (chunk prefix ends, all /256)
  CvtA ca;
  ca.d[0] = { mk,   mkmv,           2097152, 30, 0 };
  ca.d[1] = { mv,   mkmv + M_ * D_, 4194304, 30, 0 };
  ca.d[2] = { inw,  inpj,           4980736, 30, 0 };
  ca.d[3] = { gW1,  gW1b,           5505024, 30, 0 };
  ca.d[4] = { gW2,  gW2b,           5767168, 30, 0 };
  ca.d[5] = { iW1,  iW1b,           6815744, 30, 0 };
  ca.d[6] = { iW2,  iW2b,           7340032, 30, 0 };
  ca.d[7] = { outw, outwb,          7602176, 30, 0 };
  ca.d[8] = { x,    xms,            7618560, 10, 2 * D_ };
  ca.d[9] = { x,    xgm,            7634944, 10, 2 * D_ };
  cvt_flat<<<dim3(29824), 256, 0, stream>>>(ca);

  // 2) W^T (bf16) for the weight-combine GEMMs
  transpose_cvt3<<<dim3(32, 32, 3), 256, 0, stream>>>(Wq, Wk, Wv, WT);

  // 3) combined biases bc = Wi @ b + bi
  bias_combine<<<dim3(D_, 3), 256, 0, stream>>>(inw, inb, bq, bk, bv, bc);

  // 4) Wc_z = Wi_z @ W_z (batched 1024^3)
  gemm_big<0><<<dim3(8, 8, 3), 256, 0, stream>>>(
      inpj, D_, (int64_t)D_ * D_, WT, D_, (int64_t)D_ * D_,
      Wc, D_, (int64_t)D_ * D_, nullptr, nullptr, 0, D_);

  // 5) kh = mk @ Wck^T + bck (row-major) ; vhT = (mv @ Wcv^T + bcv)^T
  gemm_big<1><<<dim3(1024), 256, 0, stream>>>(
      mkmv, D_, (int64_t)M_ * D_, Wc + (int64_t)D_ * D_, D_, (int64_t)D_ * D_,
      khvh, D_, (int64_t)M_ * D_, vhT, bc + D_, D_, D_);

  // 6) qh = (x @ Wcq^T + bcq) * 1/8
  gemm_thin<4, 0, bf16><<<dim3(16, 1, 1), 256, 0, stream>>>(
      xms, 2 * D_, 0, Wc, D_, 0, qh, D_, 0, 0, bc, 0.125f, nullptr, 0, D_);

  // 7) scores[h][b][m] (fp32)
  gemm_thin<2, 0, float><<<dim3(128, 1, 16), 256, 0, stream>>>(
      qh, D_, 64, khvh, D_, 64, scores, M_, (int64_t)B_ * M_, 0,
      nullptr, 1.0f, nullptr, 0, 64);

  // 8) softmax -> attn (bf16)
  softmax_kernel<<<dim3(H_ * B_), 256, 0, stream>>>(scores, attn);

  // 9) ctx partials (split-K x8 per head) + reduce
  gemm_thin<4, 0, float><<<dim3(1, 8, 16), 256, 0, stream>>>(
      attn, M_, (int64_t)B_ * M_, vhT, M_, (int64_t)64 * M_,
      part, 64, (int64_t)8 * 4096, 4096, nullptr, 1.0f, nullptr, 0, 1024);
  ctx_reduce<<<dim3(256), 256, 0, stream>>>(part, ctx);

  // 10) memory_signal -> xms[:, D:]
  gemm_thin<4, 0, bf16><<<dim3(16, 1, 1), 256, 0, stream>>>(
      ctx, D_, 0, outwb, D_, 0, xms + D_, 2 * D_, 0, 0, outb, 1.0f,
      nullptr, 0, D_);

  // 11) g1 = relu([x,ms] @ gW1^T + gb1)
  gemm_thin<4, 1, bf16><<<dim3(16, 1, 1), 256, 0, stream>>>(
      xms, 2 * D_, 0, gW1b, 2 * D_, 0, g1, D_, 0, 0, gb1, 1.0f,
      nullptr, 0, 2 * D_);

  // 12) gated = sigmoid(g1 @ gW2^T + gb2) * ms -> xgm[:, D:]
  gemm_thin<4, 2, bf16><<<dim3(16, 1, 1), 256, 0, stream>>>(
      g1, D_, 0, gW2b, D_, 0, xgm + D_, 2 * D_, 0, 0, gb2, 1.0f,
      xms + D_, 2 * D_, D_);

  // 13) h1 = relu([x,gated] @ iW1^T + ib1)
  gemm_thin<4, 1, bf16><<<dim3(32, 1, 1), 256, 0, stream>>>(
      xgm, 2 * D_, 0, iW1b, 2 * D_, 0, h1, 2 * D_, 0, 0, ib1, 1.0f,
      nullptr, 0, 2 * D_);

  // 14) out = h1 @ iW2^T + ib2 (fp32)
  gemm_thin<4, 0, float><<<dim3(16, 1, 1), 256, 0, stream>>>(
      h1, 2 * D_, 0, iW2b, 2 * D_, 0, (float*)d_out, D_, 0, 0, ib2, 1.0f,
      nullptr, 0, 2 * D_);
}